// Round 1
// baseline (523.038 us; speedup 1.0000x reference)
//
#include <hip/hip_runtime.h>

#define NTOK 4096
#define KK   3276   // int(4096 * 0.8)

__device__ __forceinline__ unsigned key_of(float f) {
    unsigned u = __float_as_uint(f);
    return (u & 0x80000000u) ? ~u : (u | 0x80000000u);
}

// qkv1[o][c][hw] = sum_t wq[o][t] * x[(t*32+c)*1024 + hw]   (o in [0,12), c in [0,32))
__global__ void k_qkv_pointwise(const float* __restrict__ x, const float* __restrict__ wq,
                                float* __restrict__ qkv1) {
    int i = blockIdx.x * blockDim.x + threadIdx.x;
    if (i >= 12 * 32 * 1024) return;
    int hw = i & 1023;
    int c  = (i >> 10) & 31;
    int o  = i >> 15;
    const float* wqo = wq + o * 4;
    float acc = wqo[0] * x[(0 * 32 + c) * 1024 + hw];
    acc = fmaf(wqo[1], x[(1 * 32 + c) * 1024 + hw], acc);
    acc = fmaf(wqo[2], x[(2 * 32 + c) * 1024 + hw], acc);
    acc = fmaf(wqo[3], x[(3 * 32 + c) * 1024 + hw], acc);
    qkv1[i] = acc;
}

// depthwise (3x3 spatial, zero pad) then scatter into head layout [8][4][4096]
__global__ void k_dw_scatter(const float* __restrict__ qkv1, const float* __restrict__ wdw,
                             float* __restrict__ qh, float* __restrict__ kh,
                             float* __restrict__ vh) {
    int i = blockIdx.x * blockDim.x + threadIdx.x;
    if (i >= 12 * 32 * 1024) return;
    int hw = i & 1023;
    int wcol = hw & 31, hrow = hw >> 5;
    int c = (i >> 10) & 31;
    int o = i >> 15;
    const float* base = qkv1 + ((o * 32 + c) << 10);
    const float* wd = wdw + o * 9;
    float acc = 0.f;
    #pragma unroll
    for (int dy = -1; dy <= 1; ++dy) {
        int hh = hrow + dy;
        if (hh < 0 || hh > 31) continue;
        #pragma unroll
        for (int dx = -1; dx <= 1; ++dx) {
            int ww = wcol + dx;
            if (ww < 0 || ww > 31) continue;
            acc = fmaf(wd[(dy + 1) * 3 + (dx + 1)], base[hh * 32 + ww], acc);
        }
    }
    int g = o >> 2, t = o & 3;          // g: 0=q 1=k 2=v ; t = depth index within group
    int head = c >> 2, cph = c & 3;
    int n = hw * 4 + t;                  // token index, t fastest
    float* dst = (g == 0) ? qh : (g == 1) ? kh : vh;
    dst[((head << 2) + cph) * NTOK + n] = acc;
}

// L2-normalize each of the 32 q rows and 32 k rows (length 4096) in place
__global__ void k_l2norm(float* __restrict__ qh, float* __restrict__ kh) {
    __shared__ float red[4];
    int row = blockIdx.x;                // 0..63
    float* p = (row < 32) ? (qh + row * NTOK) : (kh + (row - 32) * NTOK);
    int tid = threadIdx.x;               // 256
    float ss = 0.f;
    for (int m = tid; m < NTOK; m += 256) { float v = p[m]; ss = fmaf(v, v, ss); }
    for (int off = 32; off > 0; off >>= 1) ss += __shfl_down(ss, off, 64);
    if ((tid & 63) == 0) red[tid >> 6] = ss;
    __syncthreads();
    float tot = red[0] + red[1] + red[2] + red[3];
    float inv = 1.f / fmaxf(sqrtf(tot), 1e-12f);
    for (int m = tid; m < NTOK; m += 256) p[m] *= inv;
}

// One block per (head, row n): scores -> exact top-k threshold (radix select)
// -> masked softmax -> PV.  outp layout: [head][cph][n]
__global__ __launch_bounds__(256) void k_attn(const float* __restrict__ qh,
                                              const float* __restrict__ kh,
                                              const float* __restrict__ vh,
                                              const float* __restrict__ temp,
                                              float* __restrict__ outp) {
    __shared__ float s[NTOK];            // 16 KB score row
    __shared__ unsigned hist[256];
    __shared__ float red[20];
    __shared__ float sq[4];
    __shared__ float sM;
    __shared__ unsigned s_dig, s_need, s_cnt;

    int bid = blockIdx.x;
    int head = bid >> 12;
    int n = bid & 4095;
    int tid = threadIdx.x;
    const float* kb = kh + head * 4 * NTOK;
    const float* vb = vh + head * 4 * NTOK;
    if (tid < 4) sq[tid] = qh[head * 4 * NTOK + tid * NTOK + n];
    __syncthreads();
    float q0 = sq[0], q1 = sq[1], q2 = sq[2], q3 = sq[3];
    float tmp = temp[head];

    // Phase 1: scores + row max
    float lmax = -INFINITY;
    for (int m = tid; m < NTOK; m += 256) {
        float val = q0 * kb[m];
        val = fmaf(q1, kb[NTOK + m], val);
        val = fmaf(q2, kb[2 * NTOK + m], val);
        val = fmaf(q3, kb[3 * NTOK + m], val);
        val *= tmp;
        s[m] = val;
        lmax = fmaxf(lmax, val);
    }
    for (int off = 32; off > 0; off >>= 1) lmax = fmaxf(lmax, __shfl_down(lmax, off, 64));
    if ((tid & 63) == 0) red[tid >> 6] = lmax;
    __syncthreads();
    if (tid == 0) sM = fmaxf(fmaxf(red[0], red[1]), fmaxf(red[2], red[3]));
    __syncthreads();
    float M = sM;

    // Phase 2: MSB-first radix select for the KK-th largest key
    unsigned need = KK;
    unsigned prefix = 0;
    for (int pass = 0; pass < 4; ++pass) {
        int shift = 24 - 8 * pass;
        hist[tid] = 0;
        __syncthreads();
        unsigned hmask = (pass == 0) ? 0u : (0xFFFFFFFFu << (shift + 8));
        for (int m = tid; m < NTOK; m += 256) {
            unsigned key = key_of(s[m]);
            if ((key & hmask) == prefix)
                atomicAdd(&hist[(key >> shift) & 255u], 1u);
        }
        __syncthreads();
        // suffix (descending) inclusive scan over 256 bins
        for (int d = 1; d < 256; d <<= 1) {
            unsigned add = (tid + d < 256) ? hist[tid + d] : 0u;
            __syncthreads();
            hist[tid] += add;
            __syncthreads();
        }
        unsigned sfx  = hist[tid];
        unsigned sfxn = (tid < 255) ? hist[tid + 1] : 0u;
        if (sfx >= need && sfxn < need) { s_dig = (unsigned)tid; s_need = need - sfxn; }
        __syncthreads();
        prefix |= s_dig << shift;
        need = s_need;
        __syncthreads();
    }
    unsigned tau = prefix;       // exact key of KK-th largest
    unsigned needEq = need;      // how many tied-at-tau entries are selected

    if (tid == 0) s_cnt = 0;
    __syncthreads();
    unsigned lc = 0;
    for (int m = tid; m < NTOK; m += 256) lc += (key_of(s[m]) == tau) ? 1u : 0u;
    if (lc) atomicAdd(&s_cnt, lc);
    __syncthreads();
    float scaleEq = (float)needEq / (float)s_cnt;

    // Phase 3: masked softmax numerator/denominator fused with PV
    float denom = 0.f, a0 = 0.f, a1 = 0.f, a2 = 0.f, a3 = 0.f;
    for (int m = tid; m < NTOK; m += 256) {
        float sv = s[m];
        unsigned key = key_of(sv);
        if (key >= tau) {
            float w = __expf(sv - M);
            if (key == tau) w *= scaleEq;
            denom += w;
            a0 = fmaf(w, vb[m], a0);
            a1 = fmaf(w, vb[NTOK + m], a1);
            a2 = fmaf(w, vb[2 * NTOK + m], a2);
            a3 = fmaf(w, vb[3 * NTOK + m], a3);
        }
    }
    for (int off = 32; off > 0; off >>= 1) {
        denom += __shfl_down(denom, off, 64);
        a0 += __shfl_down(a0, off, 64);
        a1 += __shfl_down(a1, off, 64);
        a2 += __shfl_down(a2, off, 64);
        a3 += __shfl_down(a3, off, 64);
    }
    __syncthreads();
    if ((tid & 63) == 0) {
        int wv = tid >> 6;
        red[wv] = denom; red[4 + wv] = a0; red[8 + wv] = a1;
        red[12 + wv] = a2; red[16 + wv] = a3;
    }
    __syncthreads();
    if (tid == 0) {
        float D = red[0] + red[1] + red[2] + red[3];
        float invD = 1.f / D;
        outp[(head * 4 + 0) * NTOK + n] = (red[4]  + red[5]  + red[6]  + red[7])  * invD;
        outp[(head * 4 + 1) * NTOK + n] = (red[8]  + red[9]  + red[10] + red[11]) * invD;
        outp[(head * 4 + 2) * NTOK + n] = (red[12] + red[13] + red[14] + red[15]) * invD;
        outp[(head * 4 + 3) * NTOK + n] = (red[16] + red[17] + red[18] + red[19]) * invD;
    }
}

// Rearrange attn output to spatial channel layout and apply 1x1 projection.
// out[o][p] = sum_ch wp[o][ch] * ao[head(ch)][cph(ch)][p*4 + t(ch)],  ch = t*32 + head*4 + cph
__global__ void k_proj(const float* __restrict__ ao, const float* __restrict__ wp,
                       float* __restrict__ out) {
    __shared__ float chin[128];
    int p = blockIdx.x;            // pixel 0..1023
    int tid = threadIdx.x;         // 128
    int t = tid >> 5;
    int c = tid & 31;
    chin[tid] = ao[c * NTOK + (p << 2) + t];   // (head<<2)+cph == c
    __syncthreads();
    const float* wr = wp + tid * 128;
    float acc = 0.f;
    #pragma unroll 8
    for (int ch = 0; ch < 128; ++ch) acc = fmaf(wr[ch], chin[ch], acc);
    out[tid * 1024 + p] = acc;
}

extern "C" void kernel_launch(void* const* d_in, const int* in_sizes, int n_in,
                              void* d_out, int out_size, void* d_ws, size_t ws_size,
                              hipStream_t stream) {
    const float* x    = (const float*)d_in[0];
    const float* temp = (const float*)d_in[1];
    const float* wq   = (const float*)d_in[2];
    const float* wdw  = (const float*)d_in[3];
    const float* wp   = (const float*)d_in[4];
    float* out = (float*)d_out;
    float* ws = (float*)d_ws;

    float* qkv1 = ws;                    // 12*32*1024 = 393216 floats
    float* qh   = ws + 393216;           // 8*4*4096 = 131072
    float* kh   = qh + 131072;
    float* vh   = kh + 131072;
    float* ao   = vh + 131072;           // 131072

    k_qkv_pointwise<<<1536, 256, 0, stream>>>(x, wq, qkv1);
    k_dw_scatter  <<<1536, 256, 0, stream>>>(qkv1, wdw, qh, kh, vh);
    k_l2norm      <<<64,   256, 0, stream>>>(qh, kh);
    k_attn        <<<32768,256, 0, stream>>>(qh, kh, vh, temp, ao);
    k_proj        <<<1024, 128, 0, stream>>>(ao, wp, out);
}

// Round 2
// 483.979 us; speedup vs baseline: 1.0807x; 1.0807x over previous
//
#include <hip/hip_runtime.h>

#define NTOK 4096
#define KK   3276   // int(4096 * 0.8)

__device__ __forceinline__ unsigned key_of(float f) {
    unsigned u = __float_as_uint(f);
    return (u & 0x80000000u) ? ~u : (u | 0x80000000u);
}
__device__ __forceinline__ float float_of_key(unsigned k) {
    unsigned u = (k & 0x80000000u) ? (k ^ 0x80000000u) : ~k;
    return __uint_as_float(u);
}

// qkv1[o][c][hw] = sum_t wq[o][t] * x[(t*32+c)*1024 + hw]
__global__ void k_qkv_pointwise(const float* __restrict__ x, const float* __restrict__ wq,
                                float* __restrict__ qkv1) {
    int i = blockIdx.x * blockDim.x + threadIdx.x;
    if (i >= 12 * 32 * 1024) return;
    int hw = i & 1023;
    int c  = (i >> 10) & 31;
    int o  = i >> 15;
    const float* wqo = wq + o * 4;
    float acc = wqo[0] * x[(0 * 32 + c) * 1024 + hw];
    acc = fmaf(wqo[1], x[(1 * 32 + c) * 1024 + hw], acc);
    acc = fmaf(wqo[2], x[(2 * 32 + c) * 1024 + hw], acc);
    acc = fmaf(wqo[3], x[(3 * 32 + c) * 1024 + hw], acc);
    qkv1[i] = acc;
}

// depthwise 3x3 then scatter into [head][n][cph] float4-friendly layout
__global__ void k_dw_scatter(const float* __restrict__ qkv1, const float* __restrict__ wdw,
                             float* __restrict__ qh, float* __restrict__ kh,
                             float* __restrict__ vh) {
    int i = blockIdx.x * blockDim.x + threadIdx.x;
    if (i >= 12 * 32 * 1024) return;
    int hw = i & 1023;
    int wcol = hw & 31, hrow = hw >> 5;
    int c = (i >> 10) & 31;
    int o = i >> 15;
    const float* base = qkv1 + ((o * 32 + c) << 10);
    const float* wd = wdw + o * 9;
    float acc = 0.f;
    #pragma unroll
    for (int dy = -1; dy <= 1; ++dy) {
        int hh = hrow + dy;
        if (hh < 0 || hh > 31) continue;
        #pragma unroll
        for (int dx = -1; dx <= 1; ++dx) {
            int ww = wcol + dx;
            if (ww < 0 || ww > 31) continue;
            acc = fmaf(wd[(dy + 1) * 3 + (dx + 1)], base[hh * 32 + ww], acc);
        }
    }
    int g = o >> 2, t = o & 3;
    int head = c >> 2, cph = c & 3;
    int n = hw * 4 + t;
    float* dst = (g == 0) ? qh : (g == 1) ? kh : vh;
    dst[(((head << 12) + n) << 2) + cph] = acc;   // [head][n][4]
}

// Normalize the 4 (cph) rows of one head of q or k; fold temperature into q.
__global__ void k_l2norm(float* __restrict__ qh, float* __restrict__ kh,
                         const float* __restrict__ temp) {
    __shared__ float red[16];
    int b = blockIdx.x;              // 0..15 : head = b>>1, q if !(b&1)
    int head = b >> 1;
    bool isQ = (b & 1) == 0;
    float4* p4 = (float4*)((isQ ? qh : kh) + (head << 14));
    int tid = threadIdx.x;
    float s0 = 0.f, s1 = 0.f, s2 = 0.f, s3 = 0.f;
    for (int m = tid; m < NTOK; m += 256) {
        float4 v = p4[m];
        s0 = fmaf(v.x, v.x, s0); s1 = fmaf(v.y, v.y, s1);
        s2 = fmaf(v.z, v.z, s2); s3 = fmaf(v.w, v.w, s3);
    }
    for (int off = 32; off > 0; off >>= 1) {
        s0 += __shfl_down(s0, off, 64); s1 += __shfl_down(s1, off, 64);
        s2 += __shfl_down(s2, off, 64); s3 += __shfl_down(s3, off, 64);
    }
    if ((tid & 63) == 0) {
        int w = tid >> 6;
        red[w * 4 + 0] = s0; red[w * 4 + 1] = s1; red[w * 4 + 2] = s2; red[w * 4 + 3] = s3;
    }
    __syncthreads();
    float t0 = red[0] + red[4] + red[8] + red[12];
    float t1 = red[1] + red[5] + red[9] + red[13];
    float t2 = red[2] + red[6] + red[10] + red[14];
    float t3 = red[3] + red[7] + red[11] + red[15];
    float scale = isQ ? temp[head] : 1.f;
    float i0 = scale / fmaxf(sqrtf(t0), 1e-12f);
    float i1 = scale / fmaxf(sqrtf(t1), 1e-12f);
    float i2 = scale / fmaxf(sqrtf(t2), 1e-12f);
    float i3 = scale / fmaxf(sqrtf(t3), 1e-12f);
    for (int m = tid; m < NTOK; m += 256) {
        float4 v = p4[m];
        v.x *= i0; v.y *= i1; v.z *= i2; v.w *= i3;
        p4[m] = v;
    }
}

// One block per (head, row n). Scores/keys live in registers (16 per thread).
__global__ __launch_bounds__(256) void k_attn(const float* __restrict__ qh,
                                              const float* __restrict__ kh,
                                              const float* __restrict__ vh,
                                              float* __restrict__ outp) {
    __shared__ unsigned hist[256];
    __shared__ float red[44];
    __shared__ float sM;
    __shared__ unsigned s_dig, s_need;

    int bid = blockIdx.x;
    int head = bid >> 12;
    int n = bid & 4095;
    int tid = threadIdx.x;
    int lane = tid & 63;

    const float4* kb4 = (const float4*)kh + (head << 12);
    const float4* vb4 = (const float4*)vh + (head << 12);
    float4 qv = ((const float4*)qh)[(head << 12) + n];   // uniform

    // Phase 1: scores -> keys in registers, row max
    unsigned keys[16];
    float lmax = -INFINITY;
    #pragma unroll
    for (int j = 0; j < 16; ++j) {
        int m = tid + (j << 8);
        float4 kv = kb4[m];
        float val = qv.x * kv.x;
        val = fmaf(qv.y, kv.y, val);
        val = fmaf(qv.z, kv.z, val);
        val = fmaf(qv.w, kv.w, val);
        keys[j] = key_of(val);
        lmax = fmaxf(lmax, val);
    }
    for (int off = 32; off > 0; off >>= 1) lmax = fmaxf(lmax, __shfl_down(lmax, off, 64));
    if ((tid & 63) == 0) red[tid >> 6] = lmax;
    __syncthreads();
    float M = fmaxf(fmaxf(red[0], red[1]), fmaxf(red[2], red[3]));

    // Phase 2: 4-pass MSB radix select (8-bit digits), candidates in a bitmask
    unsigned cand = 0xFFFFu;
    unsigned need = KK;
    unsigned tau = 0;
    #pragma unroll
    for (int pass = 0; pass < 4; ++pass) {
        int shift = 24 - 8 * pass;
        hist[tid] = 0;
        __syncthreads();
        #pragma unroll
        for (int j = 0; j < 16; ++j) {
            if (cand & (1u << j))
                atomicAdd(&hist[(keys[j] >> shift) & 255u], 1u);
        }
        __syncthreads();
        if (tid < 64) {
            // wave-0 suffix scan of 256 bins (4 bins per lane)
            unsigned h0 = hist[4 * lane + 0], h1 = hist[4 * lane + 1];
            unsigned h2 = hist[4 * lane + 2], h3 = hist[4 * lane + 3];
            unsigned ls = h0 + h1 + h2 + h3;
            unsigned S = ls;
            #pragma unroll
            for (int off = 1; off < 64; off <<= 1) {
                unsigned v = __shfl_down(S, off, 64);
                if (lane + off < 64) S += v;
            }
            unsigned above = S - ls;                 // suffix of lanes > lane
            unsigned sfx0 = S;
            unsigned sfx1 = S - h0;
            unsigned sfx2 = sfx1 - h1;
            unsigned sfx3 = above + h3;
            if (sfx0 >= need && sfx1 < need) { s_dig = 4u * lane + 0u; s_need = need - sfx1; }
            if (sfx1 >= need && sfx2 < need) { s_dig = 4u * lane + 1u; s_need = need - sfx2; }
            if (sfx2 >= need && sfx3 < need) { s_dig = 4u * lane + 2u; s_need = need - sfx3; }
            if (sfx3 >= need && above < need) { s_dig = 4u * lane + 3u; s_need = need - above; }
        }
        __syncthreads();
        unsigned dig = s_dig;
        need = s_need;
        tau |= dig << shift;
        if (pass < 3) {
            #pragma unroll
            for (int j = 0; j < 16; ++j) {
                if ((cand & (1u << j)) && (((keys[j] >> shift) & 255u) != dig))
                    cand &= ~(1u << j);
            }
        }
    }
    unsigned needEq = need;   // tied-at-tau entries selected

    // Phase 3: masked softmax + PV, tie handling fused (separate eq accumulators)
    float denom = 0.f, a0 = 0.f, a1 = 0.f, a2 = 0.f, a3 = 0.f;
    float de = 0.f, e0 = 0.f, e1 = 0.f, e2 = 0.f, e3 = 0.f;
    float cntf = 0.f;
    #pragma unroll
    for (int j = 0; j < 16; ++j) {
        unsigned key = keys[j];
        if (key < tau) continue;
        int m = tid + (j << 8);
        float sv = float_of_key(key);
        float w = __expf(sv - M);
        float4 vv = vb4[m];
        if (key == tau) {
            cntf += 1.f; de += w;
            e0 = fmaf(w, vv.x, e0); e1 = fmaf(w, vv.y, e1);
            e2 = fmaf(w, vv.z, e2); e3 = fmaf(w, vv.w, e3);
        } else {
            denom += w;
            a0 = fmaf(w, vv.x, a0); a1 = fmaf(w, vv.y, a1);
            a2 = fmaf(w, vv.z, a2); a3 = fmaf(w, vv.w, a3);
        }
    }
    for (int off = 32; off > 0; off >>= 1) {
        denom += __shfl_down(denom, off, 64);
        a0 += __shfl_down(a0, off, 64); a1 += __shfl_down(a1, off, 64);
        a2 += __shfl_down(a2, off, 64); a3 += __shfl_down(a3, off, 64);
        de += __shfl_down(de, off, 64);
        e0 += __shfl_down(e0, off, 64); e1 += __shfl_down(e1, off, 64);
        e2 += __shfl_down(e2, off, 64); e3 += __shfl_down(e3, off, 64);
        cntf += __shfl_down(cntf, off, 64);
    }
    if ((tid & 63) == 0) {
        float* r = red + (tid >> 6) * 11;
        r[0] = denom; r[1] = a0; r[2] = a1; r[3] = a2; r[4] = a3;
        r[5] = de; r[6] = e0; r[7] = e1; r[8] = e2; r[9] = e3; r[10] = cntf;
    }
    __syncthreads();
    if (tid == 0) {
        float rD = 0, r0 = 0, r1 = 0, r2 = 0, r3 = 0;
        float qD = 0, q0 = 0, q1 = 0, q2 = 0, q3 = 0, qc = 0;
        #pragma unroll
        for (int w = 0; w < 4; ++w) {
            float* r = red + w * 11;
            rD += r[0]; r0 += r[1]; r1 += r[2]; r2 += r[3]; r3 += r[4];
            qD += r[5]; q0 += r[6]; q1 += r[7]; q2 += r[8]; q3 += r[9]; qc += r[10];
        }
        float scaleEq = (float)needEq / qc;
        float D = rD + scaleEq * qD;
        float invD = 1.f / D;
        outp[((head << 2) + 0) * NTOK + n] = (r0 + scaleEq * q0) * invD;
        outp[((head << 2) + 1) * NTOK + n] = (r1 + scaleEq * q1) * invD;
        outp[((head << 2) + 2) * NTOK + n] = (r2 + scaleEq * q2) * invD;
        outp[((head << 2) + 3) * NTOK + n] = (r3 + scaleEq * q3) * invD;
    }
}

// out[o][p] = sum_ch wp[o][ch] * ao[head(ch)*4+cph(ch)][p*4 + t(ch)], ch = t*32 + head*4 + cph
__global__ void k_proj(const float* __restrict__ ao, const float* __restrict__ wp,
                       float* __restrict__ out) {
    __shared__ float chin[128];
    int p = blockIdx.x;
    int tid = threadIdx.x;       // 128
    int t = tid >> 5;
    int c = tid & 31;
    chin[tid] = ao[c * NTOK + (p << 2) + t];
    __syncthreads();
    const float* wr = wp + tid * 128;
    float acc = 0.f;
    #pragma unroll 8
    for (int ch = 0; ch < 128; ++ch) acc = fmaf(wr[ch], chin[ch], acc);
    out[tid * 1024 + p] = acc;
}

extern "C" void kernel_launch(void* const* d_in, const int* in_sizes, int n_in,
                              void* d_out, int out_size, void* d_ws, size_t ws_size,
                              hipStream_t stream) {
    const float* x    = (const float*)d_in[0];
    const float* temp = (const float*)d_in[1];
    const float* wq   = (const float*)d_in[2];
    const float* wdw  = (const float*)d_in[3];
    const float* wp   = (const float*)d_in[4];
    float* out = (float*)d_out;
    float* ws = (float*)d_ws;

    float* qkv1 = ws;                    // 393216 floats
    float* qh   = ws + 393216;           // 131072 ([head][n][4])
    float* kh   = qh + 131072;
    float* vh   = kh + 131072;
    float* ao   = vh + 131072;           // [c][n]

    k_qkv_pointwise<<<1536, 256, 0, stream>>>(x, wq, qkv1);
    k_dw_scatter  <<<1536, 256, 0, stream>>>(qkv1, wdw, qh, kh, vh);
    k_l2norm      <<<16,   256, 0, stream>>>(qh, kh, temp);
    k_attn        <<<32768,256, 0, stream>>>(qh, kh, vh, ao);
    k_proj        <<<1024, 128, 0, stream>>>(ao, wp, out);
}